// Round 11
// baseline (533.606 us; speedup 1.0000x reference)
//
#include <hip/hip_runtime.h>
#include <hip/hip_bf16.h>

typedef __attribute__((ext_vector_type(8))) short short8;
typedef __attribute__((ext_vector_type(4))) float floatx4;

#define C_INN 256
#define T_N   8
#define H_N   56
#define W_N   56
#define C_OUTN 256
#define HW_N  (H_N * W_N)
#define THW   (T_N * HW_N)
#define NTAP  9
#define LDX_S 40   // bf16 elems per px row (32 + 8 pad)

// -------- prep: weight (C_OUT, C_IN, 1, 3, 3) fp32 -> wb in MFMA-fragment order
// wb layout: [g4 = cg*4+mtile][chunk = (tap*4+quad)*64 + r][e=0..7]  (16B chunks)
// chunk content = A[o = mtile*64+r][tap][ci = cg*32 + quad*8 + e]
__global__ void prep_weight(const float* __restrict__ w, __hip_bfloat16* __restrict__ wb) {
    int idx = blockIdx.x * blockDim.x + threadIdx.x;
    if (idx >= C_OUTN * NTAP * C_INN) return;
    int e    = idx & 7;
    int c    = (idx >> 3) % 2304;      // chunk within (cg,mtile) slice
    int g4   = (idx >> 3) / 2304;      // cg*4 + mtile
    int r    = c & 63;
    int tq   = c >> 6;                 // tap*4 + quad, 0..35
    int quad = tq & 3, tap = tq >> 2;
    int cg = g4 >> 2, mtile = g4 & 3;
    int o  = mtile * 64 + r;
    int ci = cg * 32 + quad * 8 + e;
    wb[idx] = __float2bfloat16(w[(o * C_INN + ci) * NTAP + tap]);
}

// -------- main: M=64 x N=256 tile; A direct-from-L2 (no lA); only X in LDS (27.2 KB);
// T14 X-reg-prefetch; explicit 1-tap-ahead af/bf software pipeline; (256,2) for regs --------
__global__ __launch_bounds__(256, 2) void tada_conv(
    const float* __restrict__ x, const float* __restrict__ alpha,
    const __hip_bfloat16* __restrict__ wb, const float* __restrict__ bias,
    float* __restrict__ out)
{
    // lX[px][ci32 (+8 pad)]: 340 px (10h x 34w halo) -> 27200 B (the ONLY LDS)
    __shared__ __hip_bfloat16 lX[340 * LDX_S];

    const int tid = threadIdx.x;

    // ---- XCD-chunked bijective swizzle: 1792 = 8 XCDs x 224; chunk = 4 bt-slices ----
    const int id  = blockIdx.x;
    const int nid = (id & 7) * 224 + (id >> 3);
    const int mtile = nid & 3;             // 0..3   (c_out tile of 64)
    const int ntile = (nid >> 2) % 14;     // 0..13  (7 h-tiles x 2 w-tiles)
    const int bt    = nid / 56;            // 0..31
    const int b = bt >> 3, t = bt & 7;
    const int h0 = (ntile % 7) * 8;
    const int w0 = (ntile / 7) * 32;

    const int wn   = tid >> 6;             // wave 0..3 -> px quarter
    const int lane = tid & 63;
    const int col = lane & 15, quad = lane >> 4;

    // X staging decomposition: 4 ci-octets x 64 px-lanes (b128 writes)
    const int cil4 = tid & 3;   // 0..3  -> ci octet
    const int pxl  = tid >> 2;  // 0..63

    // ---- cg-invariant X halo offsets (sentinel -1 = outside image); 340 = 5*64+20 ----
    int xoff[6];
#pragma unroll
    for (int it = 0; it < 6; ++it) {
        int px = pxl + it * 64;
        int hi = px / 34;
        int wi = px - hi * 34;
        int hh = h0 - 1 + hi;
        int ww = w0 - 1 + wi;
        bool inimg = (px < 340) && ((unsigned)hh < (unsigned)H_N) && ((unsigned)ww < (unsigned)W_N);
        xoff[it] = inimg ? (hh * W_N + ww) : -1;
    }

    floatx4 acc[4][4];
#pragma unroll
    for (int i = 0; i < 4; ++i)
#pragma unroll
        for (int j = 0; j < 4; ++j)
            acc[i][j] = (floatx4){0.f, 0.f, 0.f, 0.f};

    const long xbase = ((long)b * C_INN) * THW + (long)t * HW_N;
    const int  abase = b * C_INN * T_N + t;

    // per-lane A base in wb fragment order: + cg*73728 (= 4 slices * 2304 chunks * 8)
    const __hip_bfloat16* wq = wb + ((long)mtile * 2304 + quad * 64 + col) * 8;
    // per-lane X base in lX: + ((ni>>1)+kh)*1360 + (ni&1)*640 + kw*40 per frag (imm)
    const __hip_bfloat16* lXw = lX + wn * 2720 + col * 40 + quad * 8;

    // ---- T14 prefetch state: raw fp32 X values + alpha for the NEXT cg ----
    float pX[6][8];
    float pa[8];

    auto PREFETCH = [&](int cgp) {
        const int ci0 = cgp * 32 + cil4 * 8;
#pragma unroll
        for (int j = 0; j < 8; ++j)
            pa[j] = alpha[abase + (ci0 + j) * T_N];
        const float* xc = x + xbase + (long)ci0 * THW;
#pragma unroll
        for (int it = 0; it < 6; ++it) {
            if (xoff[it] >= 0) {
                const float* xp = xc + xoff[it];
#pragma unroll
                for (int j = 0; j < 8; ++j)
                    pX[it][j] = xp[j * THW];
            } else {
#pragma unroll
                for (int j = 0; j < 8; ++j)
                    pX[it][j] = 0.f;
            }
        }
    };

    PREFETCH(0);

    for (int cg = 0; cg < 8; ++cg) {
        __syncthreads();   // previous cg's lX reads done

        // ---- write X halo: scale by alpha, cvt bf16, b128 writes ----
#pragma unroll
        for (int it = 0; it < 6; ++it) {
            int px = pxl + it * 64;
            if (it < 5 || pxl < 20) {      // px < 340
                union { __hip_bfloat16 h[8]; short8 v; } pk;
#pragma unroll
                for (int j = 0; j < 8; ++j)
                    pk.h[j] = __float2bfloat16(pX[it][j] * pa[j]);
                *reinterpret_cast<short8*>(&lX[px * LDX_S + cil4 * 8]) = pk.v;
            }
        }
        __syncthreads();   // lX staged

        // ---- issue next cg's X loads now; latency hides under this cg's MFMA ----
        if (cg < 7) PREFETCH(cg + 1);

        // ---- 9 taps, 1-tap-ahead double-buffered af (L2) + bf (LDS) pipeline ----
        const __hip_bfloat16* wcg = wq + (long)cg * 73728;   // FIX: was 18432 (missing x4)
        short8 af[2][4], bf[2][4];
#pragma unroll
        for (int mi = 0; mi < 4; ++mi)
            af[0][mi] = *(const short8*)(wcg + (mi * 16) * 8);
#pragma unroll
        for (int ni = 0; ni < 4; ++ni)
            bf[0][ni] = *(const short8*)(lXw + (ni >> 1) * 1360 + (ni & 1) * 640);

#pragma unroll
        for (int tap = 0; tap < 9; ++tap) {
            const int cur = tap & 1, nxt = cur ^ 1;   // compile-time (loop unrolled)
            if (tap < 8) {
                const int tn = tap + 1, khn = tn / 3, kwn = tn % 3;
#pragma unroll
                for (int mi = 0; mi < 4; ++mi)
                    af[nxt][mi] = *(const short8*)(wcg + (tn * 256 + mi * 16) * 8);
#pragma unroll
                for (int ni = 0; ni < 4; ++ni)
                    bf[nxt][ni] = *(const short8*)(lXw + ((ni >> 1) + khn) * 1360
                                                       + (ni & 1) * 640 + kwn * 40);
            }
#pragma unroll
            for (int mi = 0; mi < 4; ++mi)
#pragma unroll
                for (int ni = 0; ni < 4; ++ni)
                    acc[mi][ni] = __builtin_amdgcn_mfma_f32_16x16x32_bf16(
                        af[cur][mi], bf[cur][ni], acc[mi][ni], 0, 0, 0);
        }
    }

    // ---- epilogue: bias + store (C/D layout: col=lane&15, row=quad*4+reg) ----
#pragma unroll
    for (int mi = 0; mi < 4; ++mi) {
        const floatx4 bv = *(const floatx4*)(bias + mtile * 64 + mi * 16 + quad * 4);
#pragma unroll
        for (int ni = 0; ni < 4; ++ni) {
            int n  = wn * 64 + ni * 16 + col;
            int ph = n >> 5, pw = n & 31;
            if (w0 + pw < W_N) {
#pragma unroll
                for (int r = 0; r < 4; ++r) {
                    int m = mtile * 64 + mi * 16 + quad * 4 + r;
                    out[(((long)b * C_OUTN + m) * T_N + t) * HW_N + (h0 + ph) * W_N + (w0 + pw)]
                        = acc[mi][ni][r] + bv[r];
                }
            }
        }
    }
}

extern "C" void kernel_launch(void* const* d_in, const int* in_sizes, int n_in,
                              void* d_out, int out_size, void* d_ws, size_t ws_size,
                              hipStream_t stream) {
    const float* x      = (const float*)d_in[0];
    const float* alpha  = (const float*)d_in[1];
    const float* weight = (const float*)d_in[2];
    const float* bias   = (const float*)d_in[3];
    float* out = (float*)d_out;

    __hip_bfloat16* wb = (__hip_bfloat16*)d_ws;   // 256*9*256 bf16 = 1.18 MB (fragment order)

    int nprep = C_OUTN * NTAP * C_INN;
    prep_weight<<<(nprep + 255) / 256, 256, 0, stream>>>(weight, wb);

    tada_conv<<<dim3(1792), 256, 0, stream>>>(x, alpha, wb, bias, out);
}

// Round 13
// 319.687 us; speedup vs baseline: 1.6692x; 1.6692x over previous
//
#include <hip/hip_runtime.h>
#include <hip/hip_bf16.h>

typedef __attribute__((ext_vector_type(8))) short short8;
typedef __attribute__((ext_vector_type(4))) float floatx4;

#define C_INN 256
#define T_N   8
#define H_N   56
#define W_N   56
#define C_OUTN 256
#define HW_N  (H_N * W_N)
#define THW   (T_N * HW_N)
#define NTAP  9
#define LDX_S 40   // bf16 elems per px row (32 + 8 pad)

#define XS_OFF  2097152            // xs offset in workspace (wb = 1.18 MB at 0)
#define XS_BYTES ((long)32 * HW_N * C_INN * 2)   // 51,380,224

// async global->LDS, 16B per lane; LDS dest = wave-uniform base + lane*16
#define GLOAD_LDS16(gp, lp) \
  __builtin_amdgcn_global_load_lds((const __attribute__((address_space(1))) void*)(gp), \
                                   (__attribute__((address_space(3))) void*)(lp), 16, 0, 0)

// -------- prep 1: weight (C_OUT, C_IN, 1, 3, 3) fp32 -> wb for linear LDS staging
// wb layout: [g4 = cg*4+mtile][chunk = (tap*4+quad)*64 + r][e=0..7]  (16B chunks)
__global__ void prep_weight(const float* __restrict__ w, __hip_bfloat16* __restrict__ wb) {
    int idx = blockIdx.x * blockDim.x + threadIdx.x;
    if (idx >= C_OUTN * NTAP * C_INN) return;
    int e    = idx & 7;
    int c    = (idx >> 3) % 2304;
    int g4   = (idx >> 3) / 2304;
    int r    = c & 63;
    int tq   = c >> 6;
    int quad = tq & 3, tap = tq >> 2;
    int cg = g4 >> 2, mtile = g4 & 3;
    int o  = mtile * 64 + r;
    int ci = cg * 32 + quad * 8 + e;
    wb[idx] = __float2bfloat16(w[(o * C_INN + ci) * NTAP + tap]);
}

// -------- prep 2: xs[bt][hw][ci] bf16 = x * alpha, channels-last (LDS transpose) ----
__global__ void prep_xs(const float* __restrict__ x, const float* __restrict__ alpha,
                        __hip_bfloat16* __restrict__ xs) {
    __shared__ __hip_bfloat16 ls[64][72];   // [px][ci], 144B rows (16B-aligned)
    const int pt = blockIdx.x;              // 0..48  px tile of 64
    const int ct = blockIdx.y;              // 0..3   ci tile of 64
    const int bt = blockIdx.z;              // 0..31
    const int b = bt >> 3, t = bt & 7;
    const int px0 = pt * 64, ci0 = ct * 64;
    const int tid = threadIdx.x;
    const int r = tid >> 6, l = tid & 63;

    const float* xb = x + (long)b * (C_INN * THW) + (long)t * HW_N;   // + ci*THW + px
    const float* ab = alpha + b * (C_INN * T_N) + t;                  // + ci*T_N
#pragma unroll
    for (int rr2 = 0; rr2 < 8; ++rr2) {
        int c0 = r * 16 + rr2 * 2;
        int ci = ci0 + c0;
        float v0 = xb[(long)ci * THW + px0 + l]       * ab[ci * T_N];
        float v1 = xb[(long)(ci + 1) * THW + px0 + l] * ab[(ci + 1) * T_N];
        union { __hip_bfloat16 h[2]; unsigned u; } pk;
        pk.h[0] = __float2bfloat16(v0);
        pk.h[1] = __float2bfloat16(v1);
        *reinterpret_cast<unsigned*>(&ls[l][c0]) = pk.u;
    }
    __syncthreads();
    // 64 px rows x 8 ci-chunks = 512 chunks; 256 threads x 2 iters (FIX: was p<4 OOB)
#pragma unroll
    for (int p = 0; p < 2; ++p) {
        int pxl = (tid >> 3) + p * 32;
        int ch  = tid & 7;
        short8 v = *reinterpret_cast<const short8*>(&ls[pxl][ch * 8]);
        *reinterpret_cast<short8*>(xs + ((long)bt * HW_N + px0 + pxl) * C_INN + ci0 + ch * 8) = v;
    }
}

// -------- main: M=64 x N=256 tile; lA via global_load_lds; lX from xs (PRE=1, pure
// bf16 b128 copies) or from x*alpha on the fly (PRE=0, R5 legacy); XCD swizzle --------
template<int PRE>
__global__ __launch_bounds__(256, 2) void tada_conv(
    const float* __restrict__ x, const float* __restrict__ alpha,
    const __hip_bfloat16* __restrict__ xs,
    const __hip_bfloat16* __restrict__ wb, const float* __restrict__ bias,
    float* __restrict__ out)
{
    __shared__ __hip_bfloat16 lA[2304 * 8];        // 36864 B, linear 16B chunks
    __shared__ __hip_bfloat16 lX[340 * LDX_S];     // 27200 B

    const int tid = threadIdx.x;

    // XCD-chunked bijective swizzle: 1792 = 8 XCDs x 224
    const int id  = blockIdx.x;
    const int nid = (id & 7) * 224 + (id >> 3);
    const int mtile = nid & 3;
    const int ntile = (nid >> 2) % 14;
    const int bt    = nid / 56;
    const int b = bt >> 3, t = bt & 7;
    const int h0 = (ntile % 7) * 8;
    const int w0 = (ntile / 7) * 32;

    const int wn   = tid >> 6;
    const int lane = tid & 63;
    const int col = lane & 15, quad = lane >> 4;

    const int cil4 = tid & 3;   // ci octet (16B chunk)
    const int pxl  = tid >> 2;  // 0..63

    // cg-invariant halo offsets (hw index, -1 = outside)
    int xoff[6];
#pragma unroll
    for (int it = 0; it < 6; ++it) {
        int px = pxl + it * 64;
        int hi = px / 34;
        int wi = px - hi * 34;
        int hh = h0 - 1 + hi;
        int ww = w0 - 1 + wi;
        bool inimg = (px < 340) && ((unsigned)hh < (unsigned)H_N) && ((unsigned)ww < (unsigned)W_N);
        xoff[it] = inimg ? (hh * W_N + ww) : -1;
    }

    floatx4 acc[4][4];
#pragma unroll
    for (int i = 0; i < 4; ++i)
#pragma unroll
        for (int j = 0; j < 4; ++j)
            acc[i][j] = (floatx4){0.f, 0.f, 0.f, 0.f};

    const long xbase = ((long)b * C_INN) * THW + (long)t * HW_N;
    const int  abase = b * C_INN * T_N + t;

    const __hip_bfloat16* lAr = lA + quad * 512 + col * 8;       // + tap*2048 + mi*128
    const __hip_bfloat16* lXw = lX + wn * 2720 + col * 40 + quad * 8;

    // ---- T14 prefetch state ----
    short8 pXv[6];                 // PRE path: raw bf16 chunks
    float  pX[6][8];               // legacy path: raw fp32 + alpha
    float  pa[8];
    const short8 ZV = {0, 0, 0, 0, 0, 0, 0, 0};

    // PRE: per-it byte offsets into xs (cg-invariant part)
    long boff[6];
    if constexpr (PRE) {
#pragma unroll
        for (int it = 0; it < 6; ++it)
            boff[it] = (xoff[it] >= 0)
                ? ((long)bt * HW_N + xoff[it]) * (C_INN * 2) + cil4 * 16
                : -1;
    }

    auto PREFETCH = [&](int cgp) {
        if constexpr (PRE) {
#pragma unroll
            for (int it = 0; it < 6; ++it)
                pXv[it] = (boff[it] >= 0)
                    ? *reinterpret_cast<const short8*>(
                          reinterpret_cast<const char*>(xs) + boff[it] + (long)cgp * 64)
                    : ZV;
        } else {
            const int ci0 = cgp * 32 + cil4 * 8;
#pragma unroll
            for (int j = 0; j < 8; ++j)
                pa[j] = alpha[abase + (ci0 + j) * T_N];
            const float* xc = x + xbase + (long)ci0 * THW;
#pragma unroll
            for (int it = 0; it < 6; ++it) {
                if (xoff[it] >= 0) {
                    const float* xp = xc + xoff[it];
#pragma unroll
                    for (int j = 0; j < 8; ++j)
                        pX[it][j] = xp[j * THW];
                } else {
#pragma unroll
                    for (int j = 0; j < 8; ++j)
                        pX[it][j] = 0.f;
                }
            }
        }
    };

    PREFETCH(0);

    for (int cg = 0; cg < 8; ++cg) {
        __syncthreads();   // previous cg's lA/lX reads done

        // ---- stage A: 9 x global_load_lds (16B/lane), linear LDS ----
        {
            const __hip_bfloat16* wsrc = wb + ((long)(cg * 4 + mtile) * 2304) * 8;
            const int cb = wn * 64;
#pragma unroll
            for (int it = 0; it < 9; ++it) {
                GLOAD_LDS16(wsrc + (long)(it * 256 + cb + lane) * 8,
                            (char*)lA + (it * 256 + cb) * 16);
            }
        }

        // ---- write X halo into lX (b128, conflict-free) ----
#pragma unroll
        for (int it = 0; it < 6; ++it) {
            int px = pxl + it * 64;
            if (it < 5 || pxl < 20) {      // px < 340
                if constexpr (PRE) {
                    *reinterpret_cast<short8*>(&lX[px * LDX_S + cil4 * 8]) = pXv[it];
                } else {
                    union { __hip_bfloat16 h[8]; short8 v; } pk;
#pragma unroll
                    for (int j = 0; j < 8; ++j)
                        pk.h[j] = __float2bfloat16(pX[it][j] * pa[j]);
                    *reinterpret_cast<short8*>(&lX[px * LDX_S + cil4 * 8]) = pk.v;
                }
            }
        }
        __syncthreads();   // lA (vmcnt) + lX (lgkm) staged

        // ---- issue next cg's X loads; latency hides under this cg's MFMA ----
        if (cg < 7) PREFETCH(cg + 1);

        // ---- 9 taps: 8 ds_read_b128 + 16 MFMA per tap ----
#pragma unroll
        for (int kh = 0; kh < 3; ++kh) {
#pragma unroll
            for (int kw = 0; kw < 3; ++kw) {
                const int tap = kh * 3 + kw;
                short8 af[4], bf[4];
#pragma unroll
                for (int mi = 0; mi < 4; ++mi)
                    af[mi] = *(const short8*)(lAr + tap * 2048 + mi * 128);
#pragma unroll
                for (int ni = 0; ni < 4; ++ni)
                    bf[ni] = *(const short8*)(lXw + ((ni >> 1) + kh) * 1360
                                                  + (ni & 1) * 640 + kw * 40);
#pragma unroll
                for (int mi = 0; mi < 4; ++mi)
#pragma unroll
                    for (int ni = 0; ni < 4; ++ni)
                        acc[mi][ni] = __builtin_amdgcn_mfma_f32_16x16x32_bf16(
                            af[mi], bf[ni], acc[mi][ni], 0, 0, 0);
            }
        }
    }

    // ---- epilogue: bias + store (C/D layout: col=lane&15, row=quad*4+reg) ----
#pragma unroll
    for (int mi = 0; mi < 4; ++mi) {
        const floatx4 bv = *(const floatx4*)(bias + mtile * 64 + mi * 16 + quad * 4);
#pragma unroll
        for (int ni = 0; ni < 4; ++ni) {
            int n  = wn * 64 + ni * 16 + col;
            int ph = n >> 5, pw = n & 31;
            if (w0 + pw < W_N) {
#pragma unroll
                for (int r = 0; r < 4; ++r) {
                    int m = mtile * 64 + mi * 16 + quad * 4 + r;
                    out[(((long)b * C_OUTN + m) * T_N + t) * HW_N + (h0 + ph) * W_N + (w0 + pw)]
                        = acc[mi][ni][r] + bv[r];
                }
            }
        }
    }
}

extern "C" void kernel_launch(void* const* d_in, const int* in_sizes, int n_in,
                              void* d_out, int out_size, void* d_ws, size_t ws_size,
                              hipStream_t stream) {
    const float* x      = (const float*)d_in[0];
    const float* alpha  = (const float*)d_in[1];
    const float* weight = (const float*)d_in[2];
    const float* bias   = (const float*)d_in[3];
    float* out = (float*)d_out;

    __hip_bfloat16* wb = (__hip_bfloat16*)d_ws;   // 1.18 MB, fragment order

    int nprep = C_OUTN * NTAP * C_INN;
    prep_weight<<<(nprep + 255) / 256, 256, 0, stream>>>(weight, wb);

    if (ws_size >= (size_t)(XS_OFF + XS_BYTES)) {
        __hip_bfloat16* xsb = (__hip_bfloat16*)((char*)d_ws + XS_OFF);
        prep_xs<<<dim3(49, 4, 32), 256, 0, stream>>>(x, alpha, xsb);
        tada_conv<1><<<dim3(1792), 256, 0, stream>>>(x, alpha, xsb, wb, bias, out);
    } else {
        tada_conv<0><<<dim3(1792), 256, 0, stream>>>(x, alpha, nullptr, wb, bias, out);
    }
}